// Round 1
// baseline (2732.923 us; speedup 1.0000x reference)
//
#include <hip/hip_runtime.h>
#include <math.h>

#define HW   1600
#define C0   64
#define K0   2048
#define C1   256
#define K1   512

static const size_t OFF_X3  = 0;
static const size_t OFF_QX0 = 13107200;
static const size_t OFF_QX3 = 16384000;
static const size_t OFF_A0  = 29491200;
static const size_t OFF_A3  = 134348800;
static const size_t OFF_D0  = 160563200;
static const size_t OFF_D3  = 265420800;

// ---------------- kernel 0: codebook squared norms ----------------
__global__ __launch_bounds__(256) void k_esq(const float* __restrict__ vq0,
                                             const float* __restrict__ vq1,
                                             float* __restrict__ esq) {
    int r = blockIdx.x * 256 + threadIdx.x;
    if (r < K0) {
        float s = 0.f;
        for (int c = 0; c < C0; c++) { float v = vq0[r * C0 + c]; s += v * v; }
        esq[r] = s;
    } else if (r < K0 + K1) {
        int rr = r - K0;
        float s = 0.f;
        for (int c = 0; c < C1; c++) { float v = vq1[rr * C1 + c]; s += v * v; }
        esq[K0 + rr] = s;
    }
}

// ---------------- kernel A: stage-0 distances + online softmax stats ----------------
__global__ __launch_bounds__(256) void k_dist0(const float* __restrict__ x0,
                                               const float* __restrict__ cb,
                                               const float* __restrict__ esq,
                                               float* __restrict__ d0,
                                               float* __restrict__ stats) {
    __shared__ __align__(16) float xs[32][68];     // stride 272B (16B mult)
    __shared__ float xsq[32];
    __shared__ __align__(16) float esT[64][132];   // [c][kk], stride 528B
    __shared__ float rowM[32], rowS[32];

    const int t = threadIdx.x;
    const int n0 = blockIdx.x * 32;
    const int b = n0 / HW, hw0 = n0 % HW;

    for (int i = t; i < 32 * 64; i += 256) {
        int c = i >> 5, r = i & 31;
        xs[r][c] = x0[(size_t)(b * C0 + c) * HW + hw0 + r];
    }
    __syncthreads();
    if (t < 32) {
        float s = 0.f;
        for (int c = 0; c < 64; c++) { float v = xs[t][c]; s += v * v; }
        xsq[t] = s; rowM[t] = -1e30f; rowS[t] = 0.f;
    }
    __syncthreads();

    const int rg = t >> 5;   // rows rg*4..+3
    const int kg = t & 31;   // ks kg*4..+3

    for (int k0 = 0; k0 < K0; k0 += 128) {
        for (int i = t; i < 128 * 64; i += 256) {
            int c = i & 63, kk = i >> 6;
            esT[c][kk] = cb[(size_t)(k0 + kk) * C0 + c];
        }
        __syncthreads();

        float acc[4][4];
        #pragma unroll
        for (int i = 0; i < 4; i++)
            #pragma unroll
            for (int j = 0; j < 4; j++) acc[i][j] = 0.f;

        #pragma unroll 2
        for (int c = 0; c < 64; c += 4) {
            float xv[4][4];
            #pragma unroll
            for (int i = 0; i < 4; i++) {
                float4 xt = *(const float4*)&xs[rg * 4 + i][c];
                xv[i][0] = xt.x; xv[i][1] = xt.y; xv[i][2] = xt.z; xv[i][3] = xt.w;
            }
            #pragma unroll
            for (int q = 0; q < 4; q++) {
                float4 ev = *(const float4*)&esT[c + q][kg * 4];
                #pragma unroll
                for (int i = 0; i < 4; i++) {
                    acc[i][0] += xv[i][q] * ev.x;
                    acc[i][1] += xv[i][q] * ev.y;
                    acc[i][2] += xv[i][q] * ev.z;
                    acc[i][3] += xv[i][q] * ev.w;
                }
            }
        }

        float4 eq = *(const float4*)&esq[k0 + kg * 4];
        float eqv[4] = {eq.x, eq.y, eq.z, eq.w};
        float mrow[4], srow[4];
        #pragma unroll
        for (int i = 0; i < 4; i++) {
            int r = rg * 4 + i;
            float xq = xsq[r];
            float dv[4];
            #pragma unroll
            for (int j = 0; j < 4; j++) dv[j] = xq + eqv[j] - 2.f * acc[i][j];
            float4 st; st.x = dv[0]; st.y = dv[1]; st.z = dv[2]; st.w = dv[3];
            *(float4*)&d0[(size_t)(n0 + r) * K0 + k0 + kg * 4] = st;
            float m = -10.f * dv[0];
            m = fmaxf(m, -10.f * dv[1]);
            m = fmaxf(m, -10.f * dv[2]);
            m = fmaxf(m, -10.f * dv[3]);
            float s = 0.f;
            #pragma unroll
            for (int j = 0; j < 4; j++) s += __expf(-10.f * dv[j] - m);
            mrow[i] = m; srow[i] = s;
        }
        #pragma unroll
        for (int off = 1; off < 32; off <<= 1) {
            #pragma unroll
            for (int i = 0; i < 4; i++) {
                float m2 = __shfl_xor(mrow[i], off, 64);
                float s2 = __shfl_xor(srow[i], off, 64);
                float M = fmaxf(mrow[i], m2);
                srow[i] = srow[i] * __expf(mrow[i] - M) + s2 * __expf(m2 - M);
                mrow[i] = M;
            }
        }
        if (kg == 0) {
            #pragma unroll
            for (int i = 0; i < 4; i++) {
                int r = rg * 4 + i;
                float Mo = rowM[r], So = rowS[r];
                float M = fmaxf(Mo, mrow[i]);
                rowS[r] = So * __expf(Mo - M) + srow[i] * __expf(mrow[i] - M);
                rowM[r] = M;
            }
        }
        __syncthreads();
    }
    if (t < 32) {
        stats[(size_t)(n0 + t) * 2]     = rowM[t];
        stats[(size_t)(n0 + t) * 2 + 1] = rowS[t];
    }
}

// ---------------- kernel B: stage-0 prob -> a0, q_feat -> qx0 ----------------
__global__ __launch_bounds__(256) void k_prob0(const float* __restrict__ x0,
                                               const float* __restrict__ cb,
                                               const float* __restrict__ stats,
                                               const int* __restrict__ iter,
                                               const float* __restrict__ d0,
                                               float* __restrict__ out) {
    __shared__ __align__(16) float es[128][68];   // [kk][c]
    __shared__ float ptT[128][33];                // [kk][r]
    __shared__ float rowMv[32], rowIS[32];

    const int t = threadIdx.x;
    const int n0 = blockIdx.x * 32;
    const int b = n0 / HW, hw0 = n0 % HW;

    if (t < 32) {
        rowMv[t] = stats[(size_t)(n0 + t) * 2];
        rowIS[t] = 1.f / stats[(size_t)(n0 + t) * 2 + 1];
    }
    __syncthreads();

    const int r1 = t >> 3;
    const int ks1 = (t & 7) * 16;
    const int rq = t & 31;
    const int cg = t >> 5;
    const float Mr1 = rowMv[r1], IS1 = rowIS[r1];

    float qf[8];
    #pragma unroll
    for (int q = 0; q < 8; q++) qf[q] = 0.f;

    float* a0 = out + OFF_A0;

    for (int k0 = 0; k0 < K0; k0 += 128) {
        for (int i = t; i < 128 * 64; i += 256) {
            int kk = i >> 6, c = i & 63;
            es[kk][c] = cb[(size_t)(k0 + kk) * C0 + c];
        }
        const float* dr = &d0[(size_t)(n0 + r1) * K0 + k0 + ks1];
        #pragma unroll
        for (int q = 0; q < 4; q++) {
            float4 dv = *(const float4*)&dr[q * 4];
            ptT[ks1 + q * 4 + 0][r1] = __expf(-10.f * dv.x - Mr1) * IS1;
            ptT[ks1 + q * 4 + 1][r1] = __expf(-10.f * dv.y - Mr1) * IS1;
            ptT[ks1 + q * 4 + 2][r1] = __expf(-10.f * dv.z - Mr1) * IS1;
            ptT[ks1 + q * 4 + 3][r1] = __expf(-10.f * dv.w - Mr1) * IS1;
        }
        __syncthreads();
        #pragma unroll
        for (int jj = 0; jj < 16; jj++) {
            int pos = jj * 256 + t;
            int kk = pos >> 5, r = pos & 31;
            a0[(size_t)(b * K0 + k0 + kk) * HW + hw0 + r] = ptT[kk][r];
        }
        #pragma unroll 8
        for (int kk = 0; kk < 128; kk++) {
            float p = ptT[kk][rq];
            float4 e0 = *(const float4*)&es[kk][cg * 8];
            float4 e1 = *(const float4*)&es[kk][cg * 8 + 4];
            qf[0] += p * e0.x; qf[1] += p * e0.y; qf[2] += p * e0.z; qf[3] += p * e0.w;
            qf[4] += p * e1.x; qf[5] += p * e1.y; qf[6] += p * e1.z; qf[7] += p * e1.w;
        }
        __syncthreads();
    }
    float gate = fmaxf((10000.f - (float)(*iter)) / 10000.f, 0.f);
    float om = 1.f - gate;
    #pragma unroll
    for (int q = 0; q < 8; q++) {
        int c = cg * 8 + q;
        size_t idx = (size_t)(b * C0 + c) * HW + hw0 + rq;
        out[OFF_QX0 + idx] = gate * x0[idx] + om * qf[q];
    }
}

// ---------------- kernel C: fused head (two 1x1 convs + relu) ----------------
__global__ __launch_bounds__(256) void k_head(const float* __restrict__ w1,
                                              const float* __restrict__ b1,
                                              const float* __restrict__ w2,
                                              const float* __restrict__ b2,
                                              float* __restrict__ out) {
    __shared__ __align__(16) float xin[32][64];
    __shared__ __align__(16) float y1s[32][256];
    __shared__ __align__(16) float wst[64][68];   // union: w1T-chunk / w2T-chunk / xo

    const int t = threadIdx.x;
    const int n0 = blockIdx.x * 32;
    const int b = n0 / HW, hw0 = n0 % HW;
    const float* qx0 = out + OFF_QX0;
    float* x3 = out + OFF_X3;

    for (int i = t; i < 32 * 64; i += 256) {
        int c = i >> 5, r = i & 31;
        xin[r][c] = qx0[(size_t)(b * C0 + c) * HW + hw0 + r];
    }
    __syncthreads();

    const int rg = t >> 5;   // 4 rows
    const int og = t & 31;   // 2 outputs

    // GEMM1: y1 = relu(x @ w1^T + b1)
    for (int op = 0; op < 4; op++) {
        int ob = op * 64;
        for (int i = t; i < 64 * 64; i += 256) {
            int c = i & 63, o = i >> 6;
            wst[c][o] = w1[(size_t)(ob + o) * C0 + c];
        }
        __syncthreads();
        float2 bb = *(const float2*)&b1[ob + og * 2];
        float acc[4][2];
        #pragma unroll
        for (int i = 0; i < 4; i++) { acc[i][0] = bb.x; acc[i][1] = bb.y; }
        #pragma unroll 2
        for (int c = 0; c < 64; c += 4) {
            float xv[4][4];
            #pragma unroll
            for (int i = 0; i < 4; i++) {
                float4 xt = *(const float4*)&xin[rg * 4 + i][c];
                xv[i][0] = xt.x; xv[i][1] = xt.y; xv[i][2] = xt.z; xv[i][3] = xt.w;
            }
            #pragma unroll
            for (int q = 0; q < 4; q++) {
                float2 wv = *(const float2*)&wst[c + q][og * 2];
                #pragma unroll
                for (int i = 0; i < 4; i++) {
                    acc[i][0] += xv[i][q] * wv.x;
                    acc[i][1] += xv[i][q] * wv.y;
                }
            }
        }
        #pragma unroll
        for (int i = 0; i < 4; i++) {
            float2 st;
            st.x = fmaxf(acc[i][0], 0.f);
            st.y = fmaxf(acc[i][1], 0.f);
            *(float2*)&y1s[rg * 4 + i][ob + og * 2] = st;
        }
        __syncthreads();
    }

    // GEMM2: x3 = y1 @ w2^T + b2
    for (int p = 0; p < 4; p++) {
        int ob = p * 64;
        float2 bb = *(const float2*)&b2[ob + og * 2];
        float acc[4][2];
        #pragma unroll
        for (int i = 0; i < 4; i++) { acc[i][0] = bb.x; acc[i][1] = bb.y; }
        for (int cc0 = 0; cc0 < 256; cc0 += 64) {
            for (int i = t; i < 64 * 64; i += 256) {
                int c = i & 63, o = i >> 6;
                wst[c][o] = w2[(size_t)(ob + o) * C1 + cc0 + c];
            }
            __syncthreads();
            #pragma unroll 2
            for (int c = 0; c < 64; c += 4) {
                float yv[4][4];
                #pragma unroll
                for (int i = 0; i < 4; i++) {
                    float4 yt = *(const float4*)&y1s[rg * 4 + i][cc0 + c];
                    yv[i][0] = yt.x; yv[i][1] = yt.y; yv[i][2] = yt.z; yv[i][3] = yt.w;
                }
                #pragma unroll
                for (int q = 0; q < 4; q++) {
                    float2 wv = *(const float2*)&wst[c + q][og * 2];
                    #pragma unroll
                    for (int i = 0; i < 4; i++) {
                        acc[i][0] += yv[i][q] * wv.x;
                        acc[i][1] += yv[i][q] * wv.y;
                    }
                }
            }
            __syncthreads();
        }
        #pragma unroll
        for (int i = 0; i < 4; i++)
            *(float2*)&wst[0][0 + (size_t)(rg * 4 + i) * 68 + og * 2] =
                make_float2(acc[i][0], acc[i][1]);
        __syncthreads();
        for (int i = t; i < 32 * 64; i += 256) {
            int o = i >> 5, r = i & 31;
            x3[(size_t)(b * C1 + ob + o) * HW + hw0 + r] = wst[0][(size_t)r * 68 + o];
        }
        __syncthreads();
    }
}

// ---------------- kernel D: stage-1 distances + stats ----------------
__global__ __launch_bounds__(256) void k_dist1(const float* __restrict__ cb,
                                               const float* __restrict__ esq,
                                               const float* __restrict__ x3,
                                               float* __restrict__ d3,
                                               float* __restrict__ stats) {
    __shared__ __align__(16) float xs[32][132];   // c-half staging
    __shared__ float esT[128][33];                // [c'][kk]
    __shared__ float xsq[32];
    __shared__ float part[32][8];
    __shared__ float rowM[32], rowS[32];

    const int t = threadIdx.x;
    const int n0 = blockIdx.x * 32;
    const int b = n0 / HW, hw0 = n0 % HW;

    {
        int r = t & 31, seg = t >> 5;
        float s = 0.f;
        for (int j = 0; j < 32; j++) {
            float v = x3[(size_t)(b * C1 + seg * 32 + j) * HW + hw0 + r];
            s += v * v;
        }
        part[r][seg] = s;
    }
    __syncthreads();
    if (t < 32) {
        float s = 0.f;
        for (int j = 0; j < 8; j++) s += part[t][j];
        xsq[t] = s; rowM[t] = -1e30f; rowS[t] = 0.f;
    }
    __syncthreads();

    const int rg = t >> 5;
    const int kg = t & 31;

    for (int k0 = 0; k0 < K1; k0 += 32) {
        float acc[4] = {0.f, 0.f, 0.f, 0.f};
        for (int ch = 0; ch < 2; ch++) {
            for (int i = t; i < 32 * 128; i += 256) {
                int c = i & 127, kk = i >> 7;
                esT[c][kk] = cb[(size_t)(k0 + kk) * C1 + ch * 128 + c];
            }
            for (int i = t; i < 32 * 128; i += 256) {
                int ci = i >> 5, r = i & 31;
                xs[r][ci] = x3[(size_t)(b * C1 + ch * 128 + ci) * HW + hw0 + r];
            }
            __syncthreads();
            #pragma unroll 2
            for (int c = 0; c < 128; c += 4) {
                float ev[4];
                #pragma unroll
                for (int q = 0; q < 4; q++) ev[q] = esT[c + q][kg];
                #pragma unroll
                for (int i = 0; i < 4; i++) {
                    float4 xt = *(const float4*)&xs[rg * 4 + i][c];
                    acc[i] += xt.x * ev[0] + xt.y * ev[1] + xt.z * ev[2] + xt.w * ev[3];
                }
            }
            __syncthreads();
        }
        float eqv = esq[k0 + kg];
        float mrow[4], srow[4];
        #pragma unroll
        for (int i = 0; i < 4; i++) {
            int r = rg * 4 + i;
            float dv = xsq[r] + eqv - 2.f * acc[i];
            d3[(size_t)(n0 + r) * K1 + k0 + kg] = dv;
            mrow[i] = -10.f * dv; srow[i] = 1.f;
        }
        #pragma unroll
        for (int off = 1; off < 32; off <<= 1) {
            #pragma unroll
            for (int i = 0; i < 4; i++) {
                float m2 = __shfl_xor(mrow[i], off, 64);
                float s2 = __shfl_xor(srow[i], off, 64);
                float M = fmaxf(mrow[i], m2);
                srow[i] = srow[i] * __expf(mrow[i] - M) + s2 * __expf(m2 - M);
                mrow[i] = M;
            }
        }
        if (kg == 0) {
            #pragma unroll
            for (int i = 0; i < 4; i++) {
                int r = rg * 4 + i;
                float Mo = rowM[r], So = rowS[r];
                float M = fmaxf(Mo, mrow[i]);
                rowS[r] = So * __expf(Mo - M) + srow[i] * __expf(mrow[i] - M);
                rowM[r] = M;
            }
        }
    }
    __syncthreads();
    if (t < 32) {
        stats[(size_t)(n0 + t) * 2]     = rowM[t];
        stats[(size_t)(n0 + t) * 2 + 1] = rowS[t];
    }
}

// ---------------- kernel E: stage-1 prob -> a3, q_feat -> qx3 ----------------
__global__ __launch_bounds__(256) void k_prob1(const float* __restrict__ cb,
                                               const float* __restrict__ stats,
                                               const int* __restrict__ iter,
                                               const float* __restrict__ d3,
                                               float* __restrict__ out) {
    __shared__ __align__(16) float es[64][132];   // [kk][c-half]
    __shared__ float ptT[64][33];
    __shared__ float rowMv[32], rowIS[32];

    const int t = threadIdx.x;
    const int n0 = blockIdx.x * 32;
    const int b = n0 / HW, hw0 = n0 % HW;

    if (t < 32) {
        rowMv[t] = stats[(size_t)(n0 + t) * 2];
        rowIS[t] = 1.f / stats[(size_t)(n0 + t) * 2 + 1];
    }
    __syncthreads();

    const int r1 = t >> 3;
    const int ks1 = (t & 7) * 8;
    const int rq = t & 31;
    const int cg = t >> 5;
    const float Mr1 = rowMv[r1], IS1 = rowIS[r1];

    float qf[2][16];
    #pragma unroll
    for (int ch = 0; ch < 2; ch++)
        #pragma unroll
        for (int q = 0; q < 16; q++) qf[ch][q] = 0.f;

    const float* x3 = out + OFF_X3;
    float* a3 = out + OFF_A3;

    for (int k0 = 0; k0 < K1; k0 += 64) {
        const float* dr = &d3[(size_t)(n0 + r1) * K1 + k0 + ks1];
        float4 dv0 = *(const float4*)&dr[0];
        float4 dv1 = *(const float4*)&dr[4];
        ptT[ks1 + 0][r1] = __expf(-10.f * dv0.x - Mr1) * IS1;
        ptT[ks1 + 1][r1] = __expf(-10.f * dv0.y - Mr1) * IS1;
        ptT[ks1 + 2][r1] = __expf(-10.f * dv0.z - Mr1) * IS1;
        ptT[ks1 + 3][r1] = __expf(-10.f * dv0.w - Mr1) * IS1;
        ptT[ks1 + 4][r1] = __expf(-10.f * dv1.x - Mr1) * IS1;
        ptT[ks1 + 5][r1] = __expf(-10.f * dv1.y - Mr1) * IS1;
        ptT[ks1 + 6][r1] = __expf(-10.f * dv1.z - Mr1) * IS1;
        ptT[ks1 + 7][r1] = __expf(-10.f * dv1.w - Mr1) * IS1;
        for (int i = t; i < 64 * 128; i += 256) {
            int c = i & 127, kk = i >> 7;
            es[kk][c] = cb[(size_t)(k0 + kk) * C1 + c];
        }
        __syncthreads();
        #pragma unroll
        for (int jj = 0; jj < 8; jj++) {
            int pos = jj * 256 + t;
            int kk = pos >> 5, r = pos & 31;
            a3[(size_t)(b * K1 + k0 + kk) * HW + hw0 + r] = ptT[kk][r];
        }
        #pragma unroll 4
        for (int kk = 0; kk < 64; kk++) {
            float p = ptT[kk][rq];
            #pragma unroll
            for (int q = 0; q < 4; q++) {
                float4 e = *(const float4*)&es[kk][cg * 16 + q * 4];
                qf[0][q * 4 + 0] += p * e.x;
                qf[0][q * 4 + 1] += p * e.y;
                qf[0][q * 4 + 2] += p * e.z;
                qf[0][q * 4 + 3] += p * e.w;
            }
        }
        __syncthreads();
        for (int i = t; i < 64 * 128; i += 256) {
            int c = i & 127, kk = i >> 7;
            es[kk][c] = cb[(size_t)(k0 + kk) * C1 + 128 + c];
        }
        __syncthreads();
        #pragma unroll 4
        for (int kk = 0; kk < 64; kk++) {
            float p = ptT[kk][rq];
            #pragma unroll
            for (int q = 0; q < 4; q++) {
                float4 e = *(const float4*)&es[kk][cg * 16 + q * 4];
                qf[1][q * 4 + 0] += p * e.x;
                qf[1][q * 4 + 1] += p * e.y;
                qf[1][q * 4 + 2] += p * e.z;
                qf[1][q * 4 + 3] += p * e.w;
            }
        }
        __syncthreads();
    }
    float gate = fmaxf((10000.f - (float)(*iter)) / 10000.f, 0.f);
    float om = 1.f - gate;
    #pragma unroll
    for (int ch = 0; ch < 2; ch++) {
        #pragma unroll
        for (int q = 0; q < 16; q++) {
            int c = ch * 128 + cg * 16 + q;
            size_t idx = (size_t)(b * C1 + c) * HW + hw0 + rq;
            out[OFF_QX3 + idx] = gate * x3[idx] + om * qf[ch][q];
        }
    }
}

extern "C" void kernel_launch(void* const* d_in, const int* in_sizes, int n_in,
                              void* d_out, int out_size, void* d_ws, size_t ws_size,
                              hipStream_t stream) {
    (void)in_sizes; (void)n_in; (void)out_size; (void)ws_size;
    const float* x0  = (const float*)d_in[0];
    const float* vq0 = (const float*)d_in[1];
    const float* vq1 = (const float*)d_in[2];
    const float* w1  = (const float*)d_in[3];
    const float* b1  = (const float*)d_in[4];
    const float* w2  = (const float*)d_in[5];
    const float* b2  = (const float*)d_in[6];
    const int*   it  = (const int*)d_in[7];
    float* out = (float*)d_out;
    float* ws  = (float*)d_ws;
    float* esq0   = ws;                        // 2048
    float* esq1   = ws + 2048;                 // 512
    float* stats0 = ws + 2560;                 // 2*51200
    float* stats1 = ws + 2560 + 2 * 51200;     // 2*51200

    hipLaunchKernelGGL(k_esq,   dim3(10),   dim3(256), 0, stream, vq0, vq1, ws);
    hipLaunchKernelGGL(k_dist0, dim3(1600), dim3(256), 0, stream, x0, vq0, esq0,
                       out + OFF_D0, stats0);
    hipLaunchKernelGGL(k_prob0, dim3(1600), dim3(256), 0, stream, x0, vq0, stats0, it,
                       out + OFF_D0, out);
    hipLaunchKernelGGL(k_head,  dim3(1600), dim3(256), 0, stream, w1, b1, w2, b2, out);
    hipLaunchKernelGGL(k_dist1, dim3(1600), dim3(256), 0, stream, vq1, esq1,
                       out + OFF_X3, out + OFF_D3, stats1);
    hipLaunchKernelGGL(k_prob1, dim3(1600), dim3(256), 0, stream, vq1, stats1, it,
                       out + OFF_D3, out);
}